// Round 19
// baseline (216.483 us; speedup 1.0000x reference)
//
#include <hip/hip_runtime.h>
#include <hip/hip_bf16.h>
#include <math.h>

#define N_NODES 100000
#define N_EDGES 600000
#define F1 128
#define F2 64

#define DEG_BLOCKS   ((N_EDGES + 255) / 256)           // 2344
#define CONVW_ELEMS  (128 * 128 + 128 * 64)
#define CONVW_BLOCKS ((CONVW_ELEMS + 255) / 256)       // 96
#define XB_BLOCKS    ((N_NODES * 128) / 2048)          // 6250 (exact)
#define NBUCK        ((N_EDGES + 255) / 256)           // 2344 position buckets
#define GG_BLOCKS    (N_NODES / 16)                    // 6250 (exact)
#define GH_BLOCKS    (N_NODES / 32)                    // 3125 (exact)

typedef __attribute__((ext_vector_type(8))) short bf16x8;
typedef __attribute__((ext_vector_type(4))) float f32x4;

__device__ inline short bfbits(float x) {
    __hip_bfloat16 h = __float2bfloat16(x);
    return *reinterpret_cast<short*>(&h);
}
__device__ inline float bf2f(short u) {
    unsigned int x = ((unsigned int)(unsigned short)u) << 16;
    return __uint_as_float(x);
}

// ---------------- fused: degree+rank || weight conversion ----------------

__global__ __launch_bounds__(256) void dc_kernel(const int* __restrict__ dst, int* __restrict__ deg,
                                                 int* __restrict__ rank,
                                                 const float* __restrict__ W1, const float* __restrict__ W2,
                                                 unsigned short* __restrict__ Wt1, unsigned short* __restrict__ Wt2) {
    if (blockIdx.x < DEG_BLOCKS) {
        int e = blockIdx.x * 256 + threadIdx.x;
        if (e < N_EDGES) rank[e] = atomicAdd(&deg[dst[e]], 1);
    } else {
        int i = (blockIdx.x - DEG_BLOCKS) * 256 + threadIdx.x;
        if (i < 128 * 128) {
            int k = i / 128, n = i % 128;
            Wt1[n * 128 + k] = (unsigned short)bfbits(W1[i]);
        } else if (i < CONVW_ELEMS) {
            int j = i - 128 * 128;
            int k = j / 64, n = j % 64;
            Wt2[n * 128 + k] = (unsigned short)bfbits(W2[j]);
        }
    }
}

// ---------------- fused: dinv + region alloc (wave scan + one atomic) ----------

__global__ void prep_kernel(const int* __restrict__ deg, int* __restrict__ counter,
                            float* __restrict__ dinv, int* __restrict__ off) {
    int i = blockIdx.x * blockDim.x + threadIdx.x;
    int d = (i < N_NODES) ? deg[i] : 0;
    if (i < N_NODES) dinv[i] = rsqrtf((float)(d + 1));   // +1 self-loop
    int incl = d;
    #pragma unroll
    for (int o = 1; o < 64; o <<= 1) {
        int v = __shfl_up(incl, o);
        if ((threadIdx.x & 63) >= o) incl += v;
    }
    int base = 0;
    if ((threadIdx.x & 63) == 63) base = atomicAdd(counter, incl);
    base = __shfl(base, 63);
    if (i < N_NODES) off[i] = base + incl - d;
}

// ---------------- fused: Xb = bf16(X * dinv[row]) || fill pass-1 (position bucketing) -----
// pass1: pos = off[dst]+rank -> append (src,pos) to bucket pos>>8 (L2-hot tails).

__global__ __launch_bounds__(256) void cf_kernel(const float* __restrict__ X,
                                                 const float* __restrict__ dinv,
                                                 unsigned short* __restrict__ Xb,
                                                 const int* __restrict__ src, const int* __restrict__ dst,
                                                 const int* __restrict__ rank, const int* __restrict__ off,
                                                 int* __restrict__ tails, int2* __restrict__ buck) {
    const int tid = threadIdx.x;
    if (blockIdx.x < XB_BLOCKS) {
        const size_t f = ((size_t)blockIdx.x * 256 + tid) * 8;
        const int row = (int)(f >> 7);
        const float dv = dinv[row];
        const float4 v0 = *(const float4*)(X + f);
        const float4 v1 = *(const float4*)(X + f + 4);
        bf16x8 t;
        t[0] = bfbits(v0.x * dv); t[1] = bfbits(v0.y * dv);
        t[2] = bfbits(v0.z * dv); t[3] = bfbits(v0.w * dv);
        t[4] = bfbits(v1.x * dv); t[5] = bfbits(v1.y * dv);
        t[6] = bfbits(v1.z * dv); t[7] = bfbits(v1.w * dv);
        *(bf16x8*)(Xb + f) = t;
    } else {
        int e = (blockIdx.x - XB_BLOCKS) * 256 + tid;
        if (e < N_EDGES) {
            int s = src[e], d = dst[e];
            int pos = off[d] + rank[e];
            int b = pos >> 8;
            int slot = atomicAdd(&tails[b], 1);
            buck[b * 256 + slot] = make_int2(s, pos);
        }
    }
}

// ---------------- fill pass-2: bucket -> csr (XCD-local 1KB regions) ----------------

__global__ __launch_bounds__(256) void p2_kernel(const int2* __restrict__ buck,
                                                 int* __restrict__ csr_src) {
    const int b = blockIdx.x;
    const int cnt = min(256, N_EDGES - b * 256);
    if (threadIdx.x < cnt) {
        int2 v = buck[b * 256 + threadIdx.x];
        csr_src[v.y] = v.x;
    }
}

// ---------------- fused: gather(ÂX) + W1 GEMM (+b1,relu) + W2 GEMM -> xw2' ----------------
// Block = 256 thr, 16 nodes. phase1: agg = dn*(sum Xb[s] + Xb[n]) -> H (16x128 bf16 LDS).
// phase2a: H @ Wt1 + b1, relu -> H2 (16x128). phase2b: H2 @ Wt2 * dinv -> xw2'.

__global__ __launch_bounds__(256) void gg_kernel(const unsigned short* __restrict__ Xb,
                                                 const float* __restrict__ dinv,
                                                 const int* __restrict__ off,
                                                 const int* __restrict__ deg,
                                                 const int* __restrict__ csr_src,
                                                 const float* __restrict__ b1,
                                                 const unsigned short* __restrict__ Wt1,
                                                 const unsigned short* __restrict__ Wt2,
                                                 unsigned short* __restrict__ xw2) {
    __shared__ unsigned short H[16 * 128];    // 4KB
    __shared__ unsigned short H2[16 * 128];   // 4KB
    char* Hb  = (char*)H;
    char* H2b = (char*)H2;
    const int tid = threadIdx.x;
    const int nl = tid >> 4;          // node_local 0..15
    const int c  = tid & 15;          // bf16x8 chunk 0..15
    const int n  = blockIdx.x * 16 + nl;   // grid exact

    const float dn = dinv[n];
    float acc[8];
    {
        const bf16x8 v = *(const bf16x8*)(Xb + (size_t)n * 128 + c * 8);
        #pragma unroll
        for (int i = 0; i < 8; i++) acc[i] = bf2f(v[i]);   // self-loop (prescaled)
    }
    const int e0 = off[n];
    const int e1 = e0 + deg[n];
    for (int j = e0; j < e1; j += 4) {
        int s[4];
        #pragma unroll
        for (int u = 0; u < 4; u++) {
            const int jj = j + u;
            s[u] = csr_src[(jj < e1) ? jj : (e1 - 1)];
        }
        float m[4]; bf16x8 v[4];
        #pragma unroll
        for (int u = 0; u < 4; u++) {
            m[u] = (j + u < e1) ? 1.f : 0.f;
            v[u] = *(const bf16x8*)(Xb + (size_t)s[u] * 128 + c * 8);
        }
        #pragma unroll
        for (int u = 0; u < 4; u++) {
            #pragma unroll
            for (int i = 0; i < 8; i++) acc[i] += bf2f(v[u][i]) * m[u];
        }
    }
    {
        bf16x8 o;
        #pragma unroll
        for (int i = 0; i < 8; i++) o[i] = bfbits(dn * acc[i]);   // row of ÂX
        *(bf16x8*)(Hb + nl * 256 + ((c * 16) ^ ((nl & 7) << 4))) = o;
    }
    __syncthreads();

    // phase 2a: H @ Wt1 -> relu(+b1) -> H2. wave w covers cols [w*32, w*32+32).
    const int w   = tid >> 6;
    const int l   = tid & 63;
    const int l16 = l & 15;
    const int kg  = l >> 4;
    bf16x8 a[4];
    #pragma unroll
    for (int ks = 0; ks < 4; ks++)
        a[ks] = *(const bf16x8*)(Hb + l16 * 256 + ((kg * 16 + ks * 64) ^ ((l16 & 7) << 4)));
    #pragma unroll
    for (int t = 0; t < 2; t++) {
        const int colbase = w * 32 + t * 16;
        const unsigned short* wp = Wt1 + (size_t)(colbase + l16) * 128 + kg * 8;
        f32x4 acc2 = (f32x4){0.f, 0.f, 0.f, 0.f};
        #pragma unroll
        for (int ks = 0; ks < 4; ks++) {
            bf16x8 bb = *(const bf16x8*)(wp + ks * 32);
            acc2 = __builtin_amdgcn_mfma_f32_16x16x32_bf16(bb, a[ks], acc2, 0, 0, 0);
        }
        const int col0 = colbase + kg * 4;   // node = l16 owns cols col0..col0+3
        short4 pk;
        pk.x = bfbits(fmaxf(acc2[0] + b1[col0 + 0], 0.f));
        pk.y = bfbits(fmaxf(acc2[1] + b1[col0 + 1], 0.f));
        pk.z = bfbits(fmaxf(acc2[2] + b1[col0 + 2], 0.f));
        pk.w = bfbits(fmaxf(acc2[3] + b1[col0 + 3], 0.f));
        *(short4*)(H2b + l16 * 256 + ((col0 * 2) ^ ((l16 & 7) << 4))) = pk;
    }
    __syncthreads();

    // phase 2b: H2 @ Wt2 -> * dinv[node] -> xw2'. wave w covers cols [w*16, w*16+16).
    bf16x8 a2[4];
    #pragma unroll
    for (int ks = 0; ks < 4; ks++)
        a2[ks] = *(const bf16x8*)(H2b + l16 * 256 + ((kg * 16 + ks * 64) ^ ((l16 & 7) << 4)));
    const unsigned short* wp2 = Wt2 + (size_t)(w * 16 + l16) * 128 + kg * 8;
    f32x4 acc3 = (f32x4){0.f, 0.f, 0.f, 0.f};
    #pragma unroll
    for (int ks = 0; ks < 4; ks++) {
        bf16x8 bb = *(const bf16x8*)(wp2 + ks * 32);
        acc3 = __builtin_amdgcn_mfma_f32_16x16x32_bf16(bb, a2[ks], acc3, 0, 0, 0);
    }
    const int node = blockIdx.x * 16 + l16;
    const float dv = dinv[node];
    short4 pk;
    pk.x = bfbits(acc3[0] * dv); pk.y = bfbits(acc3[1] * dv);
    pk.z = bfbits(acc3[2] * dv); pk.w = bfbits(acc3[3] * dv);
    *(short4*)(xw2 + (size_t)node * 64 + w * 16 + kg * 4) = pk;
}

// ---------------- fused: gather layer-2 (prescaled rows) + head ----------------

__global__ __launch_bounds__(256) void gh_kernel(const unsigned short* __restrict__ xw2,
                                                 const float* __restrict__ dinv,
                                                 const int* __restrict__ off,
                                                 const int* __restrict__ deg,
                                                 const int* __restrict__ csr_src,
                                                 const float* __restrict__ b2,
                                                 const float* __restrict__ Wh1,
                                                 const float* __restrict__ bh1,
                                                 const float* __restrict__ Wh2,
                                                 const float* __restrict__ bh2,
                                                 float* __restrict__ out) {
    __shared__ float h2s[32 * 68];   // 8.5KB, padded stride
    __shared__ float W1s[64 * 16];
    __shared__ float W2s[16];
    __shared__ float b1s[16];
    const int tid = threadIdx.x;

    ((float4*)W1s)[tid] = ((const float4*)Wh1)[tid];     // 1024 floats
    if (tid < 16) { W2s[tid] = Wh2[tid]; b1s[tid] = bh1[tid]; }

    // phase 1: gather (8 lanes per node, 32 nodes)
    const int nl = tid >> 3;          // 0..31
    const int c  = tid & 7;           // 0..7
    const int n  = blockIdx.x * 32 + nl;   // grid exact

    const float dn = dinv[n];
    float acc[8];
    {
        const bf16x8 v = *(const bf16x8*)(xw2 + (size_t)n * 64 + c * 8);
        #pragma unroll
        for (int i = 0; i < 8; i++) acc[i] = bf2f(v[i]);   // self-loop (prescaled)
    }
    const int e0 = off[n];
    const int e1 = e0 + deg[n];
    for (int j = e0; j < e1; j += 4) {
        int s[4];
        #pragma unroll
        for (int u = 0; u < 4; u++) {
            const int jj = j + u;
            s[u] = csr_src[(jj < e1) ? jj : (e1 - 1)];
        }
        float m[4]; bf16x8 v[4];
        #pragma unroll
        for (int u = 0; u < 4; u++) {
            m[u] = (j + u < e1) ? 1.f : 0.f;
            v[u] = *(const bf16x8*)(xw2 + (size_t)s[u] * 64 + c * 8);
        }
        #pragma unroll
        for (int u = 0; u < 4; u++) {
            #pragma unroll
            for (int i = 0; i < 8; i++) acc[i] += bf2f(v[u][i]) * m[u];
        }
    }
    // h2 = relu(dn*acc + b2), bf16 round-trip, widen to f32 in LDS
    float4 f0, f1;
    f0.x = bf2f(bfbits(fmaxf(dn * acc[0] + b2[c * 8 + 0], 0.f)));
    f0.y = bf2f(bfbits(fmaxf(dn * acc[1] + b2[c * 8 + 1], 0.f)));
    f0.z = bf2f(bfbits(fmaxf(dn * acc[2] + b2[c * 8 + 2], 0.f)));
    f0.w = bf2f(bfbits(fmaxf(dn * acc[3] + b2[c * 8 + 3], 0.f)));
    f1.x = bf2f(bfbits(fmaxf(dn * acc[4] + b2[c * 8 + 4], 0.f)));
    f1.y = bf2f(bfbits(fmaxf(dn * acc[5] + b2[c * 8 + 5], 0.f)));
    f1.z = bf2f(bfbits(fmaxf(dn * acc[6] + b2[c * 8 + 6], 0.f)));
    f1.w = bf2f(bfbits(fmaxf(dn * acc[7] + b2[c * 8 + 7], 0.f)));
    *(float4*)&h2s[nl * 68 + c * 8]     = f0;
    *(float4*)&h2s[nl * 68 + c * 8 + 4] = f1;
    __syncthreads();

    // phase 2: head, 16 lanes/node, two node-sets
    const int l  = tid & 15;
    const int nn = tid >> 4;          // 0..15
    #pragma unroll
    for (int ss = 0; ss < 2; ss++) {
        const int node_l = ss * 16 + nn;
        float s = b1s[l];
        #pragma unroll 8
        for (int k = 0; k < 64; k++)
            s += h2s[node_l * 68 + k] * W1s[k * 16 + l];
        float g = 0.5f * s * (1.f + erff(s * 0.70710678118654752f));
        float p = g * W2s[l];
        p += __shfl_xor(p, 1);
        p += __shfl_xor(p, 2);
        p += __shfl_xor(p, 4);
        p += __shfl_xor(p, 8);
        if (l == 0) {
            const float z = p + bh2[0];
            out[blockIdx.x * 32 + node_l] = 1.f / (1.f + expf(-z));
        }
    }
}

// ---------------- launch ----------------

extern "C" void kernel_launch(void* const* d_in, const int* in_sizes, int n_in,
                              void* d_out, int out_size, void* d_ws, size_t ws_size,
                              hipStream_t stream) {
    const float* x   = (const float*)d_in[0];
    const int*   ei  = (const int*)d_in[1];
    const float* W1  = (const float*)d_in[2];
    const float* b1  = (const float*)d_in[3];
    const float* W2  = (const float*)d_in[4];
    const float* b2  = (const float*)d_in[5];
    const float* Wh1 = (const float*)d_in[6];
    const float* bh1 = (const float*)d_in[7];
    const float* Wh2 = (const float*)d_in[8];
    const float* bh2 = (const float*)d_in[9];
    float* out = (float*)d_out;

    const int* srcA = ei;             // edge_index[0]
    const int* dstA = ei + N_EDGES;   // edge_index[1]

    char* ws = (char*)d_ws;
    const size_t MB = 1u << 20;
    float* dinv    = (float*)(ws);                    // N f32
    int*   deg     = (int*)  (ws + MB / 2);           // N i32, then counter, then tails
    int*   counter = deg + N_NODES;                   // 1 i32
    int*   tails   = counter + 1;                     // NBUCK i32
    int*   off     = (int*)  (ws + MB);               // N i32
    int*   rank    = (int*)  (ws + MB + MB / 2);      // E i32 (2.4MB)
    int*   csr_src = (int*)  (ws + 4 * MB);           // E i32 (2.4MB)
    unsigned short* Wt1 = (unsigned short*)(ws + 7 * MB);            // 128x128 bf16
    unsigned short* Wt2 = Wt1 + 128 * 128;                           // 64x128 bf16
    unsigned short* Xb  = (unsigned short*)(ws + 8 * MB);            // X*dinv bf16 (25.6MB)
    unsigned short* xw2 = (unsigned short*)(ws + 34 * MB);           // xw2' (12.8MB)
    int2*  buck    = (int2*) (ws + 47 * MB);          // NBUCK*256 int2 (4.8MB)

    // zero deg + counter + tails
    hipMemsetAsync(deg, 0, (N_NODES + 1 + NBUCK) * sizeof(int), stream);
    dc_kernel<<<DEG_BLOCKS + CONVW_BLOCKS, 256, 0, stream>>>(dstA, deg, rank, W1, W2, Wt1, Wt2);
    prep_kernel<<<(N_NODES + 255) / 256, 256, 0, stream>>>(deg, counter, dinv, off);

    // Xb convert || fill pass-1 (bucket by position)
    cf_kernel<<<XB_BLOCKS + DEG_BLOCKS, 256, 0, stream>>>(x, dinv, Xb, srcA, dstA, rank, off, tails, buck);
    // fill pass-2 (bucket -> csr, cache-local)
    p2_kernel<<<NBUCK, 256, 0, stream>>>(buck, csr_src);

    // gather(ÂX) + W1 + W2 fused
    gg_kernel<<<GG_BLOCKS, 256, 0, stream>>>(Xb, dinv, off, deg, csr_src, b1, Wt1, Wt2, xw2);

    // gather layer-2 + head fused
    gh_kernel<<<GH_BLOCKS, 256, 0, stream>>>(xw2, dinv, off, deg, csr_src, b2,
                                             Wh1, bh1, Wh2, bh2, out);
}

// Round 20
// 154.496 us; speedup vs baseline: 1.4012x; 1.4012x over previous
//
#include <hip/hip_runtime.h>
#include <hip/hip_bf16.h>
#include <math.h>

#define N_NODES 100000
#define N_EDGES 600000
#define F1 128   // conv1 width
#define F2 64    // conv2 width

#define DEG_BLOCKS   ((N_EDGES + 255) / 256)           // 2344
#define CONVW_ELEMS  (128 * 128 + 128 * 64)
#define CONVW_BLOCKS ((CONVW_ELEMS + 255) / 256)       // 96
#define MG1_BLOCKS   ((N_NODES + 63) / 64)             // 1563
#define GG_BLOCKS    (N_NODES / 16)                    // 6250 (exact)
#define GH_BLOCKS    (N_NODES / 32)                    // 3125 (exact)

typedef __attribute__((ext_vector_type(8))) short bf16x8;
typedef __attribute__((ext_vector_type(4))) float f32x4;

__device__ inline short bfbits(float x) {
    __hip_bfloat16 h = __float2bfloat16(x);
    return *reinterpret_cast<short*>(&h);
}
__device__ inline float bf2f(short u) {
    unsigned int x = ((unsigned int)(unsigned short)u) << 16;
    return __uint_as_float(x);
}

// ---------------- fused: degree+rank || weight conversion ----------------

__global__ __launch_bounds__(256) void dc_kernel(const int* __restrict__ dst, int* __restrict__ deg,
                                                 int* __restrict__ rank,
                                                 const float* __restrict__ W1, const float* __restrict__ W2,
                                                 unsigned short* __restrict__ Wt1, unsigned short* __restrict__ Wt2) {
    if (blockIdx.x < DEG_BLOCKS) {
        int e = blockIdx.x * 256 + threadIdx.x;
        if (e < N_EDGES) rank[e] = atomicAdd(&deg[dst[e]], 1);
    } else {
        int i = (blockIdx.x - DEG_BLOCKS) * 256 + threadIdx.x;
        if (i < 128 * 128) {
            int k = i / 128, n = i % 128;
            Wt1[n * 128 + k] = (unsigned short)bfbits(W1[i]);
        } else if (i < CONVW_ELEMS) {
            int j = i - 128 * 128;
            int k = j / 64, n = j % 64;
            Wt2[n * 128 + k] = (unsigned short)bfbits(W2[j]);
        }
    }
}

// ---------------- fused: dinv + region alloc (wave scan + one atomic) ----------

__global__ void prep_kernel(const int* __restrict__ deg, int* __restrict__ counter,
                            float* __restrict__ dinv, int* __restrict__ off) {
    int i = blockIdx.x * blockDim.x + threadIdx.x;
    int d = (i < N_NODES) ? deg[i] : 0;
    if (i < N_NODES) dinv[i] = rsqrtf((float)(d + 1));   // +1 self-loop
    int incl = d;
    #pragma unroll
    for (int o = 1; o < 64; o <<= 1) {
        int v = __shfl_up(incl, o);
        if ((threadIdx.x & 63) >= o) incl += v;
    }
    int base = 0;
    if ((threadIdx.x & 63) == 63) base = atomicAdd(counter, incl);
    base = __shfl(base, 63);
    if (i < N_NODES) off[i] = base + incl - d;
}

// ---------------- fused: MFMA GEMM layer-1 (C^T swap, dinv-prescaled out) || CSR fill ------
// out[row] = bf16( (X[row] @ W1) * dinv[row] )  -- folds the src-side norm into the row.

__global__ __launch_bounds__(256) void mf_kernel(const float* __restrict__ X,
                                                 const unsigned short* __restrict__ Wt,
                                                 const float* __restrict__ dinv,
                                                 unsigned short* __restrict__ out,
                                                 const int* __restrict__ src, const int* __restrict__ dst,
                                                 const int* __restrict__ rank, const int* __restrict__ off,
                                                 int* __restrict__ csr_src) {
    const int tid = threadIdx.x;
    if (blockIdx.x >= MG1_BLOCKS) {
        int e = (blockIdx.x - MG1_BLOCKS) * 256 + tid;
        if (e < N_EDGES) {
            int s = src[e], d = dst[e];
            int pos = off[d] + rank[e];
            csr_src[pos] = s;
        }
        return;
    }

    constexpr int NT = 128 / 16;
    const int wid = tid >> 6;
    const int l   = tid & 63;
    const int l16 = l & 15;
    const int kg  = l >> 4;          // 0..3

    const int row = blockIdx.x * 64 + wid * 16 + l16;
    const int rowc = (row < N_NODES) ? row : (N_NODES - 1);

    bf16x8 a[4];
    const float* xp = X + (size_t)rowc * 128 + kg * 8;
    #pragma unroll
    for (int ks = 0; ks < 4; ks++) {
        const float4 v0 = *(const float4*)(xp + ks * 32);
        const float4 v1 = *(const float4*)(xp + ks * 32 + 4);
        bf16x8 t;
        t[0] = bfbits(v0.x); t[1] = bfbits(v0.y); t[2] = bfbits(v0.z); t[3] = bfbits(v0.w);
        t[4] = bfbits(v1.x); t[5] = bfbits(v1.y); t[6] = bfbits(v1.z); t[7] = bfbits(v1.w);
        a[ks] = t;
    }

    f32x4 acc[NT];
    #pragma unroll
    for (int t = 0; t < NT; t++) acc[t] = (f32x4){0.f, 0.f, 0.f, 0.f};

    #pragma unroll
    for (int t = 0; t < NT; t++) {
        const unsigned short* wp = Wt + (size_t)(t * 16 + l16) * 128 + kg * 8;
        #pragma unroll
        for (int ks = 0; ks < 4; ks++) {
            bf16x8 bb = *(const bf16x8*)(wp + ks * 32);
            acc[t] = __builtin_amdgcn_mfma_f32_16x16x32_bf16(bb, a[ks], acc[t], 0, 0, 0);
        }
    }

    if (row < N_NODES) {
        const float dv = dinv[row];
        #pragma unroll
        for (int t = 0; t < NT; t++) {
            short4 pk;
            pk.x = bfbits(acc[t][0] * dv); pk.y = bfbits(acc[t][1] * dv);
            pk.z = bfbits(acc[t][2] * dv); pk.w = bfbits(acc[t][3] * dv);
            *(short4*)(out + (size_t)row * 128 + t * 16 + kg * 4) = pk;
        }
    }
}

// ---------------- fused: gather layer-1 (prescaled rows, no dinv[s] loads) + L2 GEMM -------
// h1[n] = relu( dinv[n] * (sum_s xw'[s] + xw'[n]) + b1 );  xw' = xw * dinv (pre-scaled).
// xw2' written pre-scaled by dinv[node] for the next gather.

__global__ __launch_bounds__(256) void gg_kernel(const unsigned short* __restrict__ xw,
                                                 const float* __restrict__ dinv,
                                                 const int* __restrict__ off,
                                                 const int* __restrict__ deg,
                                                 const int* __restrict__ csr_src,
                                                 const float* __restrict__ bias,
                                                 const unsigned short* __restrict__ Wt2,
                                                 unsigned short* __restrict__ xw2) {
    __shared__ unsigned short H[16 * 128];   // 4KB
    char* Hb = (char*)H;
    const int tid = threadIdx.x;
    const int nl = tid >> 4;          // node_local 0..15
    const int c  = tid & 15;          // bf16x8 chunk 0..15
    const int n  = blockIdx.x * 16 + nl;   // grid exact

    const float dn = dinv[n];
    float acc[8];
    {
        const bf16x8 v = *(const bf16x8*)(xw + (size_t)n * 128 + c * 8);
        #pragma unroll
        for (int i = 0; i < 8; i++) acc[i] = bf2f(v[i]);   // self-loop term (prescaled)
    }
    const int e0 = off[n];
    const int e1 = e0 + deg[n];
    int sbuf[4];
    if (e0 < e1) {
        #pragma unroll
        for (int u = 0; u < 4; u++) {
            const int jj = e0 + u;
            sbuf[u] = csr_src[(jj < e1) ? jj : (e1 - 1)];
        }
    }
    for (int j = e0; j < e1; j += 4) {
        int s[4];
        #pragma unroll
        for (int u = 0; u < 4; u++) s[u] = sbuf[u];
        const int jn = j + 4;
        if (jn < e1) {                 // prefetch next batch's csr entries
            #pragma unroll
            for (int u = 0; u < 4; u++) {
                const int jj = jn + u;
                sbuf[u] = csr_src[(jj < e1) ? jj : (e1 - 1)];
            }
        }
        float m[4]; bf16x8 v[4];
        #pragma unroll
        for (int u = 0; u < 4; u++) {
            m[u] = (j + u < e1) ? 1.f : 0.f;
            v[u] = *(const bf16x8*)(xw + (size_t)s[u] * 128 + c * 8);
        }
        #pragma unroll
        for (int u = 0; u < 4; u++) {
            #pragma unroll
            for (int i = 0; i < 8; i++) acc[i] += bf2f(v[u][i]) * m[u];
        }
    }
    bf16x8 o;
    #pragma unroll
    for (int i = 0; i < 8; i++) o[i] = bfbits(fmaxf(dn * acc[i] + bias[c * 8 + i], 0.f));
    *(bf16x8*)(Hb + nl * 256 + ((c * 16) ^ ((nl & 7) << 4))) = o;
    __syncthreads();

    // phase 2: wave w -> col-tile w of xw2; pre-scale by dinv[node]
    const int w   = tid >> 6;
    const int l   = tid & 63;
    const int l16 = l & 15;
    const int kg  = l >> 4;
    bf16x8 a[4];
    #pragma unroll
    for (int ks = 0; ks < 4; ks++)
        a[ks] = *(const bf16x8*)(Hb + l16 * 256 + ((kg * 16 + ks * 64) ^ ((l16 & 7) << 4)));
    const unsigned short* wp = Wt2 + (size_t)(w * 16 + l16) * 128 + kg * 8;
    f32x4 acc2 = (f32x4){0.f, 0.f, 0.f, 0.f};
    #pragma unroll
    for (int ks = 0; ks < 4; ks++) {
        bf16x8 bb = *(const bf16x8*)(wp + ks * 32);
        acc2 = __builtin_amdgcn_mfma_f32_16x16x32_bf16(bb, a[ks], acc2, 0, 0, 0);
    }
    const int node = blockIdx.x * 16 + l16;
    const float dv = dinv[node];
    short4 pk;
    pk.x = bfbits(acc2[0] * dv); pk.y = bfbits(acc2[1] * dv);
    pk.z = bfbits(acc2[2] * dv); pk.w = bfbits(acc2[3] * dv);
    *(short4*)(xw2 + (size_t)node * 64 + w * 16 + kg * 4) = pk;
}

// ---------------- fused: gather layer-2 (prescaled rows) + head ----------------

__global__ __launch_bounds__(256) void gh_kernel(const unsigned short* __restrict__ xw2,
                                                 const float* __restrict__ dinv,
                                                 const int* __restrict__ off,
                                                 const int* __restrict__ deg,
                                                 const int* __restrict__ csr_src,
                                                 const float* __restrict__ b2,
                                                 const float* __restrict__ Wh1,
                                                 const float* __restrict__ bh1,
                                                 const float* __restrict__ Wh2,
                                                 const float* __restrict__ bh2,
                                                 float* __restrict__ out) {
    __shared__ float h2s[32 * 68];   // 8.5KB, padded stride
    __shared__ float W1s[64 * 16];
    __shared__ float W2s[16];
    __shared__ float b1s[16];
    const int tid = threadIdx.x;

    ((float4*)W1s)[tid] = ((const float4*)Wh1)[tid];     // 1024 floats
    if (tid < 16) { W2s[tid] = Wh2[tid]; b1s[tid] = bh1[tid]; }

    // phase 1: gather (8 lanes per node, 32 nodes)
    const int nl = tid >> 3;          // 0..31
    const int c  = tid & 7;           // 0..7
    const int n  = blockIdx.x * 32 + nl;   // grid exact

    const float dn = dinv[n];
    float acc[8];
    {
        const bf16x8 v = *(const bf16x8*)(xw2 + (size_t)n * 64 + c * 8);
        #pragma unroll
        for (int i = 0; i < 8; i++) acc[i] = bf2f(v[i]);   // self-loop (prescaled)
    }
    const int e0 = off[n];
    const int e1 = e0 + deg[n];
    int sbuf[4];
    if (e0 < e1) {
        #pragma unroll
        for (int u = 0; u < 4; u++) {
            const int jj = e0 + u;
            sbuf[u] = csr_src[(jj < e1) ? jj : (e1 - 1)];
        }
    }
    for (int j = e0; j < e1; j += 4) {
        int s[4];
        #pragma unroll
        for (int u = 0; u < 4; u++) s[u] = sbuf[u];
        const int jn = j + 4;
        if (jn < e1) {
            #pragma unroll
            for (int u = 0; u < 4; u++) {
                const int jj = jn + u;
                sbuf[u] = csr_src[(jj < e1) ? jj : (e1 - 1)];
            }
        }
        float m[4]; bf16x8 v[4];
        #pragma unroll
        for (int u = 0; u < 4; u++) {
            m[u] = (j + u < e1) ? 1.f : 0.f;
            v[u] = *(const bf16x8*)(xw2 + (size_t)s[u] * 64 + c * 8);
        }
        #pragma unroll
        for (int u = 0; u < 4; u++) {
            #pragma unroll
            for (int i = 0; i < 8; i++) acc[i] += bf2f(v[u][i]) * m[u];
        }
    }
    // h2 = relu(dn*acc + b2), bf16 round-trip, widen to f32 in LDS
    float4 f0, f1;
    f0.x = bf2f(bfbits(fmaxf(dn * acc[0] + b2[c * 8 + 0], 0.f)));
    f0.y = bf2f(bfbits(fmaxf(dn * acc[1] + b2[c * 8 + 1], 0.f)));
    f0.z = bf2f(bfbits(fmaxf(dn * acc[2] + b2[c * 8 + 2], 0.f)));
    f0.w = bf2f(bfbits(fmaxf(dn * acc[3] + b2[c * 8 + 3], 0.f)));
    f1.x = bf2f(bfbits(fmaxf(dn * acc[4] + b2[c * 8 + 4], 0.f)));
    f1.y = bf2f(bfbits(fmaxf(dn * acc[5] + b2[c * 8 + 5], 0.f)));
    f1.z = bf2f(bfbits(fmaxf(dn * acc[6] + b2[c * 8 + 6], 0.f)));
    f1.w = bf2f(bfbits(fmaxf(dn * acc[7] + b2[c * 8 + 7], 0.f)));
    *(float4*)&h2s[nl * 68 + c * 8]     = f0;
    *(float4*)&h2s[nl * 68 + c * 8 + 4] = f1;
    __syncthreads();

    // phase 2: head, 16 lanes/node, two node-sets
    const int l  = tid & 15;
    const int nn = tid >> 4;          // 0..15
    #pragma unroll
    for (int ss = 0; ss < 2; ss++) {
        const int node_l = ss * 16 + nn;
        float s = b1s[l];
        #pragma unroll 8
        for (int k = 0; k < 64; k++)
            s += h2s[node_l * 68 + k] * W1s[k * 16 + l];
        float g = 0.5f * s * (1.f + erff(s * 0.70710678118654752f));
        float p = g * W2s[l];
        p += __shfl_xor(p, 1);
        p += __shfl_xor(p, 2);
        p += __shfl_xor(p, 4);
        p += __shfl_xor(p, 8);
        if (l == 0) {
            const float z = p + bh2[0];
            out[blockIdx.x * 32 + node_l] = 1.f / (1.f + expf(-z));
        }
    }
}

// ---------------- launch ----------------

extern "C" void kernel_launch(void* const* d_in, const int* in_sizes, int n_in,
                              void* d_out, int out_size, void* d_ws, size_t ws_size,
                              hipStream_t stream) {
    const float* x   = (const float*)d_in[0];
    const int*   ei  = (const int*)d_in[1];
    const float* W1  = (const float*)d_in[2];
    const float* b1  = (const float*)d_in[3];
    const float* W2  = (const float*)d_in[4];
    const float* b2  = (const float*)d_in[5];
    const float* Wh1 = (const float*)d_in[6];
    const float* bh1 = (const float*)d_in[7];
    const float* Wh2 = (const float*)d_in[8];
    const float* bh2 = (const float*)d_in[9];
    float* out = (float*)d_out;

    const int* srcA = ei;             // edge_index[0]
    const int* dstA = ei + N_EDGES;   // edge_index[1]

    char* ws = (char*)d_ws;
    const size_t MB = 1u << 20;
    float* dinv    = (float*)(ws);                    // N f32
    int*   deg     = (int*)  (ws + MB / 2);           // N i32 (+1 counter)
    int*   counter = deg + N_NODES;                   // 1 i32
    int*   off     = (int*)  (ws + MB);               // N i32
    int*   rank    = (int*)  (ws + MB + MB / 2);      // E i32 (2.4MB)
    int*   csr_src = (int*)  (ws + 4 * MB);           // E i32 (2.4MB)
    unsigned short* Wt1 = (unsigned short*)(ws + 7 * MB);            // 128x128 bf16
    unsigned short* Wt2 = Wt1 + 128 * 128;                           // 64x128 bf16
    unsigned short* bufA = (unsigned short*)(ws + 8 * MB);           // xw1' (N x 128 bf16)
    unsigned short* xw2  = (unsigned short*)(ws + 34 * MB);          // xw2' (N x 64 bf16)

    // zero deg+counter; (deg/rank || convw); prep; (mgemm1 || fill)
    hipMemsetAsync(deg, 0, (N_NODES + 1) * sizeof(int), stream);
    dc_kernel<<<DEG_BLOCKS + CONVW_BLOCKS, 256, 0, stream>>>(dstA, deg, rank, W1, W2, Wt1, Wt2);
    prep_kernel<<<(N_NODES + 255) / 256, 256, 0, stream>>>(deg, counter, dinv, off);
    mf_kernel<<<MG1_BLOCKS + DEG_BLOCKS, 256, 0, stream>>>(x, Wt1, dinv, bufA, srcA, dstA, rank, off, csr_src);

    // layer-1 aggregation + layer-2 GEMM fused
    gg_kernel<<<GG_BLOCKS, 256, 0, stream>>>(bufA, dinv, off, deg, csr_src, b1, Wt2, xw2);

    // layer-2 aggregation + head fused
    gh_kernel<<<GH_BLOCKS, 256, 0, stream>>>(xw2, dinv, off, deg, csr_src, b2,
                                             Wh1, bh1, Wh2, bh2, out);
}